// Round 3
// baseline (17824.167 us; speedup 1.0000x reference)
//
#include <hip/hip_runtime.h>
#include <hip/hip_bf16.h>

#define DI __device__ __forceinline__

// ---------- helpers ----------
static DI float bfu2f(unsigned short u) {
    return __uint_as_float(((unsigned)u) << 16);
}
static DI unsigned short f2bu(float f) {           // fp32 -> bf16 bits, RNE
    unsigned u = __float_as_uint(f);
    u += 0x7fffu + ((u >> 16) & 1u);
    return (unsigned short)(u >> 16);
}
static DI float ldB(float x) { return x; }
static DI float ldB(__hip_bfloat16 h) { return bfu2f(*(const unsigned short*)&h); }

// =====================================================================
// Generic tiled GEMM for 1x1 / k=3 "convs":
//   C[m, t] = sum_{c, tap} A[m, c*KS+tap] * B[c, t + tap - (KS-1)/2]  (+bias, relu, mask)
// A: fp32 [M, K*KS].  B: fp32 or bf16 [K, T].  C: bf16 [M, T].  T = 512.
// Tile: BM x 128, BK = 16. 256 threads, each computes (BM/16) x 8 outputs.
// =====================================================================
template<int BM, int KS, bool MASK_IN, bool RELU, bool MASK_OUT, typename TB>
static DI void gemm_body(const float* __restrict__ A,
                         const float* __restrict__ bias,
                         const TB* __restrict__ Bin,
                         __hip_bfloat16* __restrict__ Cout,
                         int len, int K, int m0, int n0)
{
    const int T = 512;
    const int KK = K * KS;
    constexpr int RM = BM / 16;           // 8 (BM=128) or 4 (BM=64)
    __shared__ float As[16][BM + 4];
    __shared__ float Bs[16][132];
    const int tid = threadIdx.x;
    const int tx = tid & 15, ty = tid >> 4;
    float acc[RM][8];
#pragma unroll
    for (int i = 0; i < RM; ++i)
#pragma unroll
        for (int j = 0; j < 8; ++j) acc[i][j] = 0.0f;

    for (int k0 = 0; k0 < KK; k0 += 16) {
        // ---- stage A tile (BM x 16 fp32, transposed) ----
        if constexpr (BM == 128) {
            const int am = tid >> 1, ak = (tid & 1) * 8;
            const float* ap = A + (size_t)(m0 + am) * KK + (k0 + ak);
            float4 w0 = *(const float4*)ap;
            float4 w1 = *(const float4*)(ap + 4);
            As[ak + 0][am] = w0.x; As[ak + 1][am] = w0.y;
            As[ak + 2][am] = w0.z; As[ak + 3][am] = w0.w;
            As[ak + 4][am] = w1.x; As[ak + 5][am] = w1.y;
            As[ak + 6][am] = w1.z; As[ak + 7][am] = w1.w;
        } else {
            const int am = tid >> 2, ak = (tid & 3) * 4;
            const float* ap = A + (size_t)(m0 + am) * KK + (k0 + ak);
            float4 w = *(const float4*)ap;
            As[ak + 0][am] = w.x;
            As[ak + 1][am] = w.y;
            As[ak + 2][am] = w.z;
            As[ak + 3][am] = w.w;
        }
        // ---- stage B tile (16 x 128 -> fp32, with conv-tap shift + masks) ----
        {
            const int bk = tid >> 4;
            const int bn = (tid & 15) * 8;
            const int kk = k0 + bk;
            int c, tap;
            if constexpr (KS == 1) { c = kk; tap = 0; }
            else                   { c = kk / KS; tap = kk - c * KS; }
            const TB* bp = Bin + (size_t)c * T;
            const int tbase = n0 + bn + tap - (KS - 1) / 2;
#pragma unroll
            for (int u = 0; u < 8; ++u) {
                const int t = tbase + u;
                float v = 0.0f;
                if (t >= 0 && t < T && (!MASK_IN || t < len)) v = ldB(bp[t]);
                Bs[bk][bn + u] = v;
            }
        }
        __syncthreads();
        // ---- compute ----
#pragma unroll
        for (int kk = 0; kk < 16; ++kk) {
            float a[RM], bv[8];
#pragma unroll
            for (int i = 0; i < RM; i += 4) {
                float4 a4 = *(const float4*)&As[kk][ty * RM + i];
                a[i] = a4.x; a[i + 1] = a4.y; a[i + 2] = a4.z; a[i + 3] = a4.w;
            }
            {
                float4 b0 = *(const float4*)&Bs[kk][tx * 4];
                float4 b1 = *(const float4*)&Bs[kk][64 + tx * 4];
                bv[0] = b0.x; bv[1] = b0.y; bv[2] = b0.z; bv[3] = b0.w;
                bv[4] = b1.x; bv[5] = b1.y; bv[6] = b1.z; bv[7] = b1.w;
            }
#pragma unroll
            for (int i = 0; i < RM; ++i)
#pragma unroll
                for (int j = 0; j < 8; ++j)
                    acc[i][j] += a[i] * bv[j];
        }
        __syncthreads();
    }
    // ---- epilogue (bf16 out) ----
#pragma unroll
    for (int i = 0; i < RM; ++i) {
        const int m = m0 + ty * RM + i;
        const float bi = bias[m];
#pragma unroll
        for (int half = 0; half < 2; ++half) {
            const int n = n0 + half * 64 + tx * 4;
            ushort4 s4;
            unsigned short* sp = &s4.x;
#pragma unroll
            for (int j = 0; j < 4; ++j) {
                float v = acc[i][half * 4 + j] + bi;
                if (RELU) v = fmaxf(v, 0.0f);
                if (MASK_OUT && (n + j) >= len) v = 0.0f;
                sp[j] = f2bu(v);
            }
            *(ushort4*)((unsigned short*)Cout + (size_t)m * T + n) = s4;
        }
    }
}

template<int BM, int KS, bool MASK_IN, bool RELU, bool MASK_OUT, typename TB>
__global__ __launch_bounds__(256) void gemm_conv(
    const float* __restrict__ A, const float* __restrict__ bias,
    const TB* __restrict__ Bin, __hip_bfloat16* __restrict__ Cout,
    const int* __restrict__ lens, int M, int K)
{
    const int T = 512;
    const int b = blockIdx.z;
    gemm_body<BM, KS, MASK_IN, RELU, MASK_OUT>(
        A, bias, Bin + (size_t)b * K * T, Cout + (size_t)b * M * T,
        lens[b], K, blockIdx.y * BM, blockIdx.x * 128);
}

// fused Q/K/V projection: blockIdx.y in [0,18): 6 row-tiles per matrix
__global__ __launch_bounds__(256) void gemm_qkv(
    const float* __restrict__ Aq, const float* __restrict__ Ak,
    const float* __restrict__ Av,
    const float* __restrict__ bq, const float* __restrict__ bk,
    const float* __restrict__ bv,
    const float* __restrict__ Bin,
    __hip_bfloat16* __restrict__ Qo, __hip_bfloat16* __restrict__ Ko,
    __hip_bfloat16* __restrict__ Vo,
    const int* __restrict__ lens)
{
    const int C = 768, T = 512;
    const int b = blockIdx.z;
    const int sel = blockIdx.y / 6;
    const int m0 = (blockIdx.y % 6) * 128;
    const float* A = (sel == 0) ? Aq : ((sel == 1) ? Ak : Av);
    const float* bb = (sel == 0) ? bq : ((sel == 1) ? bk : bv);
    __hip_bfloat16* Out = (sel == 0) ? Qo : ((sel == 1) ? Ko : Vo);
    gemm_body<128, 1, true, false, false>(
        A, bb, Bin + (size_t)b * C * T, Out + (size_t)b * C * T,
        lens[b], C, m0, blockIdx.x * 128);
}

// =====================================================================
// Attention: one block per (b, h, 16 query rows). Full 512-wide score row
// in LDS; K/V streamed through one 64x68 chunk buffer; windowed rel-pos
// bias and rel_v term computed directly (|delta| <= 4).
// =====================================================================
__global__ __launch_bounds__(256) void attn_kernel(
    const __hip_bfloat16* __restrict__ Qg, const __hip_bfloat16* __restrict__ Kg,
    const __hip_bfloat16* __restrict__ Vg,
    const float* __restrict__ relk, const float* __restrict__ relv,
    const int* __restrict__ lens, __hip_bfloat16* __restrict__ Out)
{
    const int T = 512, KC = 64, H = 12, C = 768;
    const int tid = threadIdx.x;
    const int t0 = blockIdx.x * 16;
    const int bh = blockIdx.y;
    const int b = bh / H, h = bh - b * H;
    const int len = lens[b];
    const float scale = 0.125f;  // KC^-0.5

    __shared__ float Qs[16][64];
    __shared__ float S[16][520];
    __shared__ float KV[64][68];
    __shared__ float RV[9][64];
    __shared__ float RB[16][12];
    __shared__ float Lsum[16];

    const size_t base = ((size_t)b * C + h * KC) * T;
    const unsigned short* Qu = (const unsigned short*)Qg;
    const unsigned short* Ku = (const unsigned short*)Kg;
    const unsigned short* Vu = (const unsigned short*)Vg;

    // load Q rows (pre-scaled), transpose into [r][d]
    {
        const int d = tid >> 2, rg = (tid & 3) * 4;
        ushort4 q4 = *(const ushort4*)(Qu + base + (size_t)d * T + t0 + rg);
        Qs[rg + 0][d] = bfu2f(q4.x) * scale;
        Qs[rg + 1][d] = bfu2f(q4.y) * scale;
        Qs[rg + 2][d] = bfu2f(q4.z) * scale;
        Qs[rg + 3][d] = bfu2f(q4.w) * scale;
    }
    for (int idx = tid; idx < 9 * 64; idx += 256)
        RV[idx >> 6][idx & 63] = relv[idx];
    __syncthreads();

    // windowed rel-k bias: RB[r][o] = q[t0+r] . rel_k[o],  o = delta+4
    if (tid < 144) {
        const int r = tid / 9, o = tid - (tid / 9) * 9;
        float s = 0.0f;
        for (int d = 0; d < 64; ++d)
            s += Qs[r][d] * relk[o * 64 + d];
        RB[r][o] = s;
    }
    __syncthreads();

    const int r = tid >> 4;          // 0..15 query row
    const int lx = tid & 15;         // col/d group
    const int sd = tid >> 2, sg = tid & 3;  // staging map
    const int t_abs = t0 + r;

    // ---- phase 1: scores ----
    for (int ci = 0; ci < 8; ++ci) {
        const int s0 = ci * 64;
        {
            const unsigned short* kp = Ku + base + (size_t)sd * T + s0;
#pragma unroll
            for (int j = 0; j < 4; ++j) {
                const int ss = (sg + 4 * j) * 4;
                ushort4 k4 = *(const ushort4*)(kp + ss);
                KV[ss + 0][sd] = bfu2f(k4.x);
                KV[ss + 1][sd] = bfu2f(k4.y);
                KV[ss + 2][sd] = bfu2f(k4.z);
                KV[ss + 3][sd] = bfu2f(k4.w);
            }
        }
        __syncthreads();
        float dots[4] = {0, 0, 0, 0};
#pragma unroll 4
        for (int dq = 0; dq < 16; ++dq) {
            float4 q4 = *(const float4*)&Qs[r][dq * 4];
#pragma unroll
            for (int j = 0; j < 4; ++j) {
                float4 k4 = *(const float4*)&KV[lx + 16 * j][dq * 4];
                dots[j] += q4.x * k4.x + q4.y * k4.y + q4.z * k4.z + q4.w * k4.w;
            }
        }
#pragma unroll
        for (int j = 0; j < 4; ++j) {
            const int s_abs = s0 + lx + 16 * j;
            float v = dots[j];
            const int off = s_abs - t_abs;
            if (off >= -4 && off <= 4) v += RB[r][off + 4];
            if (s_abs >= len || t_abs >= len) v = -1e4f;  // matches reference where()
            S[r][s_abs] = v;
        }
        __syncthreads();
    }

    // ---- phase 2: softmax (unnormalized; divide at the end) ----
    {
        float mx = -3.0e38f;
        for (int j = 0; j < 32; ++j) mx = fmaxf(mx, S[r][lx + 16 * j]);
#pragma unroll
        for (int m = 8; m >= 1; m >>= 1) mx = fmaxf(mx, __shfl_xor(mx, m));
        float sum = 0.0f;
        for (int j = 0; j < 32; ++j) {
            const int s = lx + 16 * j;
            const float p = __expf(S[r][s] - mx);
            S[r][s] = p;
            sum += p;
        }
#pragma unroll
        for (int m = 8; m >= 1; m >>= 1) sum += __shfl_xor(sum, m);
        if (lx == 0) Lsum[r] = sum;
        __syncthreads();
    }

    // ---- phase 3: O = P @ V ----
    float o4[4] = {0, 0, 0, 0};
    for (int ci = 0; ci < 8; ++ci) {
        const int s0 = ci * 64;
        {
            const unsigned short* vp = Vu + base + (size_t)sd * T + s0;
#pragma unroll
            for (int j = 0; j < 4; ++j) {
                const int ss = (sg + 4 * j) * 4;
                ushort4 v4 = *(const ushort4*)(vp + ss);
                KV[ss + 0][sd] = bfu2f(v4.x);
                KV[ss + 1][sd] = bfu2f(v4.y);
                KV[ss + 2][sd] = bfu2f(v4.z);
                KV[ss + 3][sd] = bfu2f(v4.w);
            }
        }
        __syncthreads();
#pragma unroll 4
        for (int s = 0; s < 64; ++s) {
            const float p = S[r][s0 + s];
            float4 v4 = *(const float4*)&KV[s][lx * 4];
            o4[0] += p * v4.x;
            o4[1] += p * v4.y;
            o4[2] += p * v4.z;
            o4[3] += p * v4.w;
        }
        __syncthreads();
    }

    // ---- rel_v term: O[t] += sum_{|d|<=4} P[t][t+d] * rel_v[d] ----
#pragma unroll
    for (int o = 0; o < 9; ++o) {
        const int s = t_abs + o - 4;
        if (s >= 0 && s < T) {
            const float p = S[r][s];
            float4 rv = *(const float4*)&RV[o][lx * 4];
            o4[0] += p * rv.x;
            o4[1] += p * rv.y;
            o4[2] += p * rv.z;
            o4[3] += p * rv.w;
        }
    }
    const float inv = 1.0f / Lsum[r];
    unsigned short* op = (unsigned short*)Out + base + (size_t)(lx * 4) * T + t_abs;
    op[0 * T] = f2bu(o4[0] * inv);
    op[1 * T] = f2bu(o4[1] * inv);
    op[2 * T] = f2bu(o4[2] * inv);
    op[3 * T] = f2bu(o4[3] * inv);
}

// =====================================================================
// Fused residual + LayerNorm over channels: X = LN(X + Y) * g + b
// X fp32 (residual stream), Y bf16. grid (T/64, B), 256 thr = 64 t x 4 cgrp
// =====================================================================
__global__ __launch_bounds__(256) void ln_kernel(
    float* __restrict__ X, const __hip_bfloat16* __restrict__ Y,
    const float* __restrict__ g, const float* __restrict__ bb)
{
    const int C = 768, T = 512;
    const int b = blockIdx.y;
    const int t0 = blockIdx.x * 64;
    const int tc = threadIdx.x & 63;
    const int cg = threadIdx.x >> 6;
    const size_t base = (size_t)b * C * T + t0 + tc;
    const unsigned short* Yu = (const unsigned short*)Y;
    float s1 = 0.0f, s2 = 0.0f;
    for (int c = cg; c < C; c += 4) {
        const size_t idx = base + (size_t)c * T;
        const float v = X[idx] + bfu2f(Yu[idx]);
        s1 += v; s2 += v * v;
    }
    __shared__ float R1[4][64], R2[4][64];
    __shared__ float Mean[64], Rstd[64];
    R1[cg][tc] = s1; R2[cg][tc] = s2;
    __syncthreads();
    if (threadIdx.x < 64) {
        const float a = R1[0][tc] + R1[1][tc] + R1[2][tc] + R1[3][tc];
        const float q = R2[0][tc] + R2[1][tc] + R2[2][tc] + R2[3][tc];
        const float mean = a * (1.0f / 768.0f);
        const float var = q * (1.0f / 768.0f) - mean * mean;
        Mean[tc] = mean;
        Rstd[tc] = rsqrtf(var + 1e-5f);
    }
    __syncthreads();
    const float mean = Mean[tc], rstd = Rstd[tc];
    for (int c = cg; c < C; c += 4) {
        const size_t idx = base + (size_t)c * T;
        const float v = X[idx] + bfu2f(Yu[idx]);
        X[idx] = (v - mean) * rstd * g[c] + bb[c];
    }
}

// ---------- in/out ----------
__global__ void copy_in(const float* __restrict__ in, float* __restrict__ out) {
    const int i = (blockIdx.x * 256 + threadIdx.x) * 4;
    *(float4*)(out + i) = *(const float4*)(in + i);
}

__global__ void finalize_kernel(const float* __restrict__ X, const int* __restrict__ lens,
                                float* __restrict__ out) {
    const int C = 768, T = 512;
    const size_t i = (size_t)blockIdx.x * 256 + threadIdx.x;
    const int t = (int)(i % T);
    const int b = (int)(i / ((size_t)C * T));
    out[i] = (t < lens[b]) ? X[i] : 0.0f;
}

// =====================================================================
extern "C" void kernel_launch(void* const* d_in, const int* in_sizes, int n_in,
                              void* d_out, int out_size, void* d_ws, size_t ws_size,
                              hipStream_t stream)
{
    (void)in_sizes; (void)n_in; (void)out_size; (void)ws_size;
    const int B = 8, C = 768, T = 512, FC = 3072, NL = 6;
    const size_t BCT = (size_t)B * C * T;

    const float* xin  = (const float*)d_in[0];
    const int*   lens = (const int*)d_in[1];
    const float* qw = (const float*)d_in[2];
    const float* qb = (const float*)d_in[3];
    const float* kw = (const float*)d_in[4];
    const float* kb = (const float*)d_in[5];
    const float* vw = (const float*)d_in[6];
    const float* vb = (const float*)d_in[7];
    const float* ow = (const float*)d_in[8];
    const float* ob = (const float*)d_in[9];
    const float* rk = (const float*)d_in[10];
    const float* rv = (const float*)d_in[11];
    const float* n1g = (const float*)d_in[12];
    const float* n1b = (const float*)d_in[13];
    const float* w1 = (const float*)d_in[14];
    const float* b1 = (const float*)d_in[15];
    const float* w2 = (const float*)d_in[16];
    const float* b2 = (const float*)d_in[17];
    const float* n2g = (const float*)d_in[18];
    const float* n2b = (const float*)d_in[19];

    // ---- lean workspace layout: 42 MB total ----
    // [ X fp32 : BCT*4 B ][ Q | K | V | AT | Y : bf16, BCT*2 B each ]
    // H (FFN hidden, bf16, 4*BCT elems) aliases Q..AT (dead by then).
    char* p0 = (char*)d_ws;
    float* X = (float*)p0;
    __hip_bfloat16* Qb = (__hip_bfloat16*)(p0 + BCT * 4);
    __hip_bfloat16* Kb = Qb + BCT;
    __hip_bfloat16* Vb = Qb + 2 * BCT;
    __hip_bfloat16* AT = Qb + 3 * BCT;
    __hip_bfloat16* Yb = Qb + 4 * BCT;
    __hip_bfloat16* Hb = Qb;          // alias: spans Q,K,V,AT exactly (FC=4C)

    copy_in<<<dim3(3072), 256, 0, stream>>>(xin, X);

    for (int i = 0; i < NL; ++i) {
        gemm_qkv<<<dim3(4, 18, 8), 256, 0, stream>>>(
            qw + (size_t)i * C * C, kw + (size_t)i * C * C, vw + (size_t)i * C * C,
            qb + i * C, kb + i * C, vb + i * C, X, Qb, Kb, Vb, lens);
        attn_kernel<<<dim3(32, 96), 256, 0, stream>>>(
            Qb, Kb, Vb, rk + (size_t)i * 9 * 64, rv + (size_t)i * 9 * 64, lens, AT);
        gemm_conv<64, 1, false, false, false><<<dim3(4, 12, 8), 256, 0, stream>>>(
            ow + (size_t)i * C * C, ob + i * C, AT, Yb, lens, C, C);
        ln_kernel<<<dim3(8, 8), 256, 0, stream>>>(X, Yb, n1g + i * C, n1b + i * C);
        gemm_conv<128, 3, true, true, true><<<dim3(4, 24, 8), 256, 0, stream>>>(
            w1 + (size_t)i * FC * C * 3, b1 + i * FC, X, Hb, lens, FC, C);
        gemm_conv<64, 3, false, false, true><<<dim3(4, 12, 8), 256, 0, stream>>>(
            w2 + (size_t)i * C * FC * 3, b2 + i * C, Hb, Yb, lens, C, FC);
        ln_kernel<<<dim3(8, 8), 256, 0, stream>>>(X, Yb, n2g + i * C, n2b + i * C);
    }

    finalize_kernel<<<dim3(12288), 256, 0, stream>>>(X, lens, (float*)d_out);
}